// Round 15
// baseline (101.863 us; speedup 1.0000x reference)
//
#include <hip/hip_runtime.h>

#define Bz 4
#define Tz 4096
#define Ez 1024
#define Hz 16
#define Sz 64
#define Dz 64
#define MTz (Bz*Tz)   // 16384

using f32x4  = __attribute__((ext_vector_type(4))) float;
using f32x16 = __attribute__((ext_vector_type(16))) float;
using short8 = __attribute__((ext_vector_type(8))) short;

__device__ __forceinline__ unsigned f2bf(float f){
  unsigned u = __builtin_bit_cast(unsigned, f);
  u = u + 0x7FFFu + ((u >> 16) & 1u);
  return (u >> 16);
}

#define GLL16(gp, lp) __builtin_amdgcn_global_load_lds( \
    (const __attribute__((address_space(1))) unsigned int*)(gp), \
    (__attribute__((address_space(3))) unsigned int*)(lp), 16, 0, 0)

// ---------------- K1 (64 blocks): Mh, a_state+bias_f ---------------------------------
__global__ __launch_bounds__(256) void k1_pre(const float* __restrict__ state,
                                              const float* __restrict__ A_w,
                                              const float* __restrict__ A_b,
                                              const float* __restrict__ C_w,
                                              const float* __restrict__ C_b,
                                              const float* __restrict__ sm,
                                              float* __restrict__ a_state,
                                              float* __restrict__ Mh,
                                              float* __restrict__ bias_f){
  __shared__ float asl[4][64];
  const int blk = blockIdx.x, tid = threadIdx.x;
  const int h = blk >> 2, q4 = blk & 3;
  { // Mh[h][d][dp] quarter
    const int d = q4*16 + (tid >> 4), dp0 = (tid & 15)*4;
    const float* cw  = C_w + (size_t)(h*64 + d)*64;
    const float* smh = sm + (size_t)h*4096 + dp0;
    float ax=0.f, ay=0.f, az=0.f, aw=0.f;
    #pragma unroll 8
    for (int s = 0; s < 64; ++s){
      float c = cw[s];
      float4 m4 = *(const float4*)&smh[s*64];
      ax += c*m4.x; ay += c*m4.y; az += c*m4.z; aw += c*m4.w;
    }
    *(float4*)&Mh[(size_t)h*4096 + d*64 + dp0] = make_float4(ax,ay,az,aw);
  }
  if (q4 == 0){
    { // a_state[h][b][s]
      const int b = tid >> 6, s = tid & 63;
      const float* aw = A_w + (size_t)(h*64 + s)*64;
      const float* st = state + (size_t)(h*4 + b)*64;
      float a0=A_b[h*64+s], a1=0.f, a2=0.f, a3=0.f;
      #pragma unroll 4
      for (int j = 0; j < 64; j += 4){
        a0 += aw[j]*st[j]; a1 += aw[j+1]*st[j+1];
        a2 += aw[j+2]*st[j+2]; a3 += aw[j+3]*st[j+3];
      }
      float v = (a0+a1)+(a2+a3);
      a_state[(h*4 + b)*64 + s] = v;
      asl[b][s] = v;
    }
    __syncthreads();
    { // bias_f[b][h*64+d]
      const int b = tid >> 6, d = tid & 63;
      const float* cw = C_w + (size_t)(h*64 + d)*64;
      float a0=C_b[h*64+d], a1=0.f, a2=0.f, a3=0.f;
      #pragma unroll 4
      for (int s = 0; s < 64; s += 4){
        a0 += cw[s]*asl[b][s]; a1 += cw[s+1]*asl[b][s+1];
        a2 += cw[s+2]*asl[b][s+2]; a3 += cw[s+3]*asl[b][s+3];
      }
      bias_f[b*1024 + h*64 + d] = (a0+a1)+(a2+a3);
    }
  }
}

// ---------------- KFUSE (4096 blocks): [0,2048) k4-role ; [2048,4096) k23-role -------
__global__ __launch_bounds__(256) void kfuse(const float* __restrict__ x,
                                             const float* __restrict__ sm,
                                             const float* __restrict__ a_state,
                                             const float* __restrict__ Wo,
                                             const float* __restrict__ Mh,
                                             const float* __restrict__ bias_f,
                                             const float* __restrict__ bo,
                                             unsigned short* __restrict__ xb,
                                             float* __restrict__ out2,
                                             unsigned short* __restrict__ Wb,
                                             float* __restrict__ constb){
  __shared__ alignas(16) char smem[27648];
  const int gblk = blockIdx.x, tid = threadIdx.x;
  if (gblk < 2048){
    // ---------------- k4 role ----------------
    unsigned short* Xs = (unsigned short*)smem;            // 128*72 shorts = 18432 B
    unsigned short* Ss = (unsigned short*)(smem + 18432);  //  64*72 shorts =  9216 B
    const int lin = gblk;
    const int tb = lin & 31, h = (lin >> 5) & 15, b = lin >> 9;
    const int lane = tid & 63, w = tid >> 6;
    const int l15 = lane & 15, l4 = lane >> 4;

    { // stage sm[h] (f32) -> Ss bf16 (row stride 72)
      const float* src = sm + (size_t)h*4096;
      #pragma unroll
      for (int cc = 0; cc < 4; ++cc){
        int c = cc*256 + tid;
        int s = c >> 4, c4 = c & 15;
        float4 v = *(const float4*)&src[s*64 + c4*4];
        uint2 pk = make_uint2(f2bf(v.x) | (f2bf(v.y)<<16), f2bf(v.z) | (f2bf(v.w)<<16));
        *(uint2*)&Ss[s*72 + c4*4] = pk;
      }
    }
    { // stage x slice -> Xs bf16 (stride 72) and xb global (row-major, 16B granules)
      const int row0 = b*Tz + tb*128;
      #pragma unroll
      for (int it = 0; it < 4; ++it){
        int id = it*256 + tid;
        int r = id >> 3, c8 = id & 7;
        const float* px = x + (size_t)(row0 + r)*1024 + h*64 + c8*8;
        float4 v0 = *(const float4*)px, v1 = *(const float4*)(px + 4);
        uint4 pk;
        pk.x = f2bf(v0.x) | (f2bf(v0.y)<<16);
        pk.y = f2bf(v0.z) | (f2bf(v0.w)<<16);
        pk.z = f2bf(v1.x) | (f2bf(v1.y)<<16);
        pk.w = f2bf(v1.z) | (f2bf(v1.w)<<16);
        *(uint4*)&Xs[r*72 + c8*8] = pk;
        *(uint4*)(xb + (size_t)(row0 + r)*1024 + h*64 + c8*8) = pk;
      }
    }
    __syncthreads();

    f32x4 acc[2][4];
    #pragma unroll
    for (int j = 0; j < 4; ++j){
      float4 as4 = *(const float4*)&a_state[(h*4 + b)*64 + j*16 + l4*4];
      f32x4 a0; a0[0]=as4.x; a0[1]=as4.y; a0[2]=as4.z; a0[3]=as4.w;
      acc[0][j] = a0; acc[1][j] = a0;
    }
    #pragma unroll
    for (int kk = 0; kk < 2; ++kk){
      short8 a[2], bb[4];
      #pragma unroll
      for (int i = 0; i < 2; ++i)
        a[i] = *(const short8*)(&Xs[(w*32 + i*16 + l15)*72 + kk*32 + l4*8]);
      #pragma unroll
      for (int j = 0; j < 4; ++j)
        bb[j] = *(const short8*)(&Ss[(j*16 + l15)*72 + kk*32 + l4*8]);
      #pragma unroll
      for (int i = 0; i < 2; ++i)
        #pragma unroll
        for (int j = 0; j < 4; ++j)
          acc[i][j] = __builtin_amdgcn_mfma_f32_16x16x32_bf16(bb[j], a[i], acc[i][j], 0, 0, 0);
    }
    const size_t base = (size_t)h*1048576 + ((size_t)b*4096 + tb*128)*64;
    #pragma unroll
    for (int i = 0; i < 2; ++i)
      #pragma unroll
      for (int j = 0; j < 4; ++j){
        float4 o = make_float4(acc[i][j][0], acc[i][j][1], acc[i][j][2], acc[i][j][3]);
        *(float4*)(out2 + base + (size_t)(w*32 + i*16 + l15)*64 + j*16 + l4*4) = o;
      }
  } else if (gblk < 3072){
    // ---------------- k23 role: Wb ----------------
    float* Mh_l = (float*)smem;
    const int blk = gblk - 2048;
    const int h = blk >> 6, ec = blk & 63;
    #pragma unroll
    for (int it = 0; it < 4; ++it){
      int c = it*256 + tid;
      *(float4*)&Mh_l[c*4] = *(const float4*)&Mh[(size_t)h*4096 + c*4];
    }
    __syncthreads();
    const int dp = tid & 63, er = tid >> 6;
    #pragma unroll
    for (int ee = 0; ee < 4; ++ee){
      const int e = ec*16 + er*4 + ee;
      const float* wo = Wo + (size_t)e*1024 + h*64;
      float a0=0.f,a1=0.f,a2=0.f,a3=0.f;
      #pragma unroll 4
      for (int d = 0; d < 64; d += 4){
        a0 += wo[d]*Mh_l[d*64+dp];     a1 += wo[d+1]*Mh_l[(d+1)*64+dp];
        a2 += wo[d+2]*Mh_l[(d+2)*64+dp]; a3 += wo[d+3]*Mh_l[(d+3)*64+dp];
      }
      Wb[(size_t)e*1024 + h*64 + dp] = (unsigned short)f2bf((a0+a1)+(a2+a3));
    }
  } else {
    // ---------------- k23 role: constb ----------------
    const int idx = (gblk - 3072)*4 + (tid >> 6), lane = tid & 63;
    const int b = idx >> 10, e = idx & 1023;
    const float4* wo = (const float4*)(Wo + (size_t)e*1024);
    const float4* bf = (const float4*)(bias_f + (size_t)b*1024);
    float acc = 0.f;
    #pragma unroll
    for (int i = 0; i < 4; ++i){
      float4 w = wo[i*64 + lane], v = bf[i*64 + lane];
      acc += w.x*v.x + w.y*v.y + w.z*v.z + w.w*v.w;
    }
    acc += __shfl_down(acc, 32); acc += __shfl_down(acc, 16); acc += __shfl_down(acc, 8);
    acc += __shfl_down(acc, 4);  acc += __shfl_down(acc, 2);  acc += __shfl_down(acc, 1);
    if (lane == 0) constb[b*1024 + e] = bo[e] + acc;
  }
}

// ---------------- K5: out = xb @ Wb^T + const  (256x128, 3-deep, 32x32x16 MFMA) ------
// 512 blocks, 512 thr (8 waves 2Mx4N: wave 128 t-rows x 32 e-cols). Same 3-buffer
// counted-vmcnt schedule as R14; MFMA shape 32x32x16 (8/tile @ ~8cyc vs 16 @ ~5cyc).
// D layout (HW-verified): col=lane&31 (t), row=(reg&3)+8*(reg>>2)+4*(lane>>5) (e).
__global__ __launch_bounds__(512, 2) void k5_gemm(const unsigned short* __restrict__ xb,
                                                  const unsigned short* __restrict__ Wb,
                                                  const float* __restrict__ constb,
                                                  float* __restrict__ out){
  __shared__ alignas(16) unsigned short ldsA[3][8192];   // 256 rows x 32 bf16 per buf
  __shared__ alignas(16) unsigned short ldsB[3][4096];   // 128 rows x 32 bf16 per buf
  const int blk = blockIdx.x;
  const int swz = (blk & 7)*64 + (blk >> 3);     // 512 blocks, 8 XCD chunks of 64
  const int bm = (swz >> 3)*256, bn = (swz & 7)*128;
  const int tid = threadIdx.x;
  const int lane = tid & 63, w = tid >> 6;       // 8 waves
  const int l31 = lane & 31, lh = lane >> 5;
  const int wr = w >> 2, wc = w & 3;             // 2 (M, 128 t-rows) x 4 (N, 32 e-cols)

  // staging source mapping: linear slot L -> logical (row r, 16B-seg g)
  const unsigned short* srcA[2];
  const unsigned short* srcB0;
  #pragma unroll
  for (int q = 0; q < 2; ++q){
    int L = q*512 + tid;
    int b = ((L>>2)&1) ^ ((L>>4)&1);
    int r = (L>>3)*2 + b;
    int g = (L&3) ^ ((((L>>3)&1)<<1) | b);
    srcA[q] = xb + (size_t)(bm + r)*1024 + g*8;
  }
  {
    int L = tid;
    int b = ((L>>2)&1) ^ ((L>>4)&1);
    int r = (L>>3)*2 + b;
    int g = (L&3) ^ ((((L>>3)&1)<<1) | b);
    srcB0 = Wb + (size_t)(bn + r)*1024 + g*8;
  }
  const int dstoff = tid*8;                       // shorts

  // prologue: stage tiles 0,1,2 (9 GLL/thread, FIFO order A0,A1,B per tile)
  #pragma unroll
  for (int t = 0; t < 3; ++t){
    GLL16(srcA[0] + t*32, &ldsA[t][dstoff]);
    GLL16(srcA[1] + t*32, &ldsA[t][4096 + dstoff]);
    GLL16(srcB0  + t*32, &ldsB[t][dstoff]);
  }
  asm volatile("s_waitcnt vmcnt(6)" ::: "memory");   // tiles 1,2 (6 loads) in flight
  __builtin_amdgcn_s_barrier();
  asm volatile("" ::: "memory");

  f32x16 acc[4] = {};
  int cur = 0, stg = 2;

  // fragment slot helpers: slot = (r*4 + seg) ^ (r&7), seg = kk*2 + lh
  const int er  = wc*32 + l31;                       // e-row in B tile (128)
  const int eo0 = ((er*4 + 0 + lh) ^ (er & 7))*8;    // kk=0
  const int eo1 = ((er*4 + 2 + lh) ^ (er & 7))*8;    // kk=1
  int to0[4], to1[4];
  #pragma unroll
  for (int i = 0; i < 4; ++i){
    int tr = wr*128 + i*32 + l31;                    // t-row in A tile (256)
    to0[i] = ((tr*4 + 0 + lh) ^ (tr & 7))*8;
    to1[i] = ((tr*4 + 2 + lh) ^ (tr & 7))*8;
  }

  for (int t = 0; t < 32; ++t){
    const unsigned short* At = &ldsA[cur][0];
    const unsigned short* Bt = &ldsB[cur][0];
    short8 bfr0, bfr1, af00, af01, af10, af11;
    // ---- phase A: B-frags + A-frags i=0,1, stage A of tile t+2, 4 MFMA
    bfr0 = *(const short8*)(Bt + eo0);
    bfr1 = *(const short8*)(Bt + eo1);
    af00 = *(const short8*)(At + to0[0]);
    af01 = *(const short8*)(At + to1[0]);
    af10 = *(const short8*)(At + to0[1]);
    af11 = *(const short8*)(At + to1[1]);
    if (t <= 29){
      GLL16(srcA[0] + (t+2)*32, &ldsA[stg][dstoff]);
      GLL16(srcA[1] + (t+2)*32, &ldsA[stg][4096 + dstoff]);
    }
    __builtin_amdgcn_s_setprio(1);
    acc[0] = __builtin_amdgcn_mfma_f32_32x32x16_bf16(bfr0, af00, acc[0], 0, 0, 0);
    acc[0] = __builtin_amdgcn_mfma_f32_32x32x16_bf16(bfr1, af01, acc[0], 0, 0, 0);
    acc[1] = __builtin_amdgcn_mfma_f32_32x32x16_bf16(bfr0, af10, acc[1], 0, 0, 0);
    acc[1] = __builtin_amdgcn_mfma_f32_32x32x16_bf16(bfr1, af11, acc[1], 0, 0, 0);
    __builtin_amdgcn_s_setprio(0);
    // ---- phase B: A-frags i=2,3, stage B of tile t+2, 4 MFMA
    af00 = *(const short8*)(At + to0[2]);
    af01 = *(const short8*)(At + to1[2]);
    af10 = *(const short8*)(At + to0[3]);
    af11 = *(const short8*)(At + to1[3]);
    if (t <= 29)
      GLL16(srcB0 + (t+2)*32, &ldsB[stg][dstoff]);
    __builtin_amdgcn_s_setprio(1);
    acc[2] = __builtin_amdgcn_mfma_f32_32x32x16_bf16(bfr0, af00, acc[2], 0, 0, 0);
    acc[2] = __builtin_amdgcn_mfma_f32_32x32x16_bf16(bfr1, af01, acc[2], 0, 0, 0);
    acc[3] = __builtin_amdgcn_mfma_f32_32x32x16_bf16(bfr0, af10, acc[3], 0, 0, 0);
    acc[3] = __builtin_amdgcn_mfma_f32_32x32x16_bf16(bfr1, af11, acc[3], 0, 0, 0);
    __builtin_amdgcn_s_setprio(0);
    // ---- boundary: keep t+2's 3 loads in flight; drain only at t=30
    if (t <= 29)      { asm volatile("s_waitcnt vmcnt(3)" ::: "memory"); }
    else if (t == 30) { asm volatile("s_waitcnt vmcnt(0)" ::: "memory"); }
    if (t < 31){
      __builtin_amdgcn_s_barrier();
      asm volatile("" ::: "memory");
    }
    cur = (cur == 2) ? 0 : cur + 1;
    stg = (stg == 2) ? 0 : stg + 1;
  }

  // epilogue: D col(l31)=t, row(reg) = (reg&3)+8*(reg>>2)+4*lh = e-local
  const int bb = bm >> 12;
  #pragma unroll
  for (int i = 0; i < 4; ++i){
    int trow = bm + wr*128 + i*32 + l31;
    #pragma unroll
    for (int q = 0; q < 4; ++q){
      int e0 = bn + wc*32 + 8*q + 4*lh;
      float4 cv = *(const float4*)&constb[bb*1024 + e0];
      float4 o = make_float4(acc[i][4*q+0] + cv.x, acc[i][4*q+1] + cv.y,
                             acc[i][4*q+2] + cv.z, acc[i][4*q+3] + cv.w);
      *(float4*)(out + (size_t)trow*1024 + e0) = o;
    }
  }
}

extern "C" void kernel_launch(void* const* d_in, const int* in_sizes, int n_in,
                              void* d_out, int out_size, void* d_ws, size_t ws_size,
                              hipStream_t stream){
  const float* x     = (const float*)d_in[0];
  const float* state = (const float*)d_in[1];
  const float* A_w   = (const float*)d_in[2];
  const float* A_b   = (const float*)d_in[3];
  const float* C_w   = (const float*)d_in[4];
  const float* C_b   = (const float*)d_in[5];
  const float* sm    = (const float*)d_in[6];
  const float* Wo    = (const float*)d_in[7];
  const float* bo    = (const float*)d_in[8];
  float* out  = (float*)d_out;
  float* out2 = out + (size_t)MTz*Ez;

  char* ws = (char*)d_ws;
  float* a_state          = (float*)(ws + 0);                 //  16 KiB
  float* Mh               = (float*)(ws + 16384);             // 256 KiB
  float* bias_f           = (float*)(ws + 278528);            //  16 KiB
  float* constb           = (float*)(ws + 294912);            //  16 KiB
  unsigned short* Wb      = (unsigned short*)(ws + 311296);   //   2 MiB
  unsigned short* xb      = (unsigned short*)(ws + 2408448);  //  32 MiB

  k1_pre<<<64, 256, 0, stream>>>(state, A_w, A_b, C_w, C_b, sm, a_state, Mh, bias_f);
  kfuse<<<4096, 256, 0, stream>>>(x, sm, a_state, Wo, Mh, bias_f, bo,
                                  xb, out2, Wb, constb);
  k5_gemm<<<512, 512, 0, stream>>>(xb, Wb, constb, out);
}

// Round 16
// 97.684 us; speedup vs baseline: 1.0428x; 1.0428x over previous
//
#include <hip/hip_runtime.h>

#define Bz 4
#define Tz 4096
#define Ez 1024
#define Hz 16
#define Sz 64
#define Dz 64
#define MTz (Bz*Tz)   // 16384

using f32x4  = __attribute__((ext_vector_type(4))) float;
using short8 = __attribute__((ext_vector_type(8))) short;

__device__ __forceinline__ unsigned f2bf(float f){
  unsigned u = __builtin_bit_cast(unsigned, f);
  u = u + 0x7FFFu + ((u >> 16) & 1u);
  return (u >> 16);
}

#define GLL16(gp, lp) __builtin_amdgcn_global_load_lds( \
    (const __attribute__((address_space(1))) unsigned int*)(gp), \
    (__attribute__((address_space(3))) unsigned int*)(lp), 16, 0, 0)

// ---------------- K1 (64 blocks): Mh, a_state+bias_f ---------------------------------
__global__ __launch_bounds__(256) void k1_pre(const float* __restrict__ state,
                                              const float* __restrict__ A_w,
                                              const float* __restrict__ A_b,
                                              const float* __restrict__ C_w,
                                              const float* __restrict__ C_b,
                                              const float* __restrict__ sm,
                                              float* __restrict__ a_state,
                                              float* __restrict__ Mh,
                                              float* __restrict__ bias_f){
  __shared__ float asl[4][64];
  const int blk = blockIdx.x, tid = threadIdx.x;
  const int h = blk >> 2, q4 = blk & 3;
  { // Mh[h][d][dp] quarter
    const int d = q4*16 + (tid >> 4), dp0 = (tid & 15)*4;
    const float* cw  = C_w + (size_t)(h*64 + d)*64;
    const float* smh = sm + (size_t)h*4096 + dp0;
    float ax=0.f, ay=0.f, az=0.f, aw=0.f;
    #pragma unroll 8
    for (int s = 0; s < 64; ++s){
      float c = cw[s];
      float4 m4 = *(const float4*)&smh[s*64];
      ax += c*m4.x; ay += c*m4.y; az += c*m4.z; aw += c*m4.w;
    }
    *(float4*)&Mh[(size_t)h*4096 + d*64 + dp0] = make_float4(ax,ay,az,aw);
  }
  if (q4 == 0){
    { // a_state[h][b][s]
      const int b = tid >> 6, s = tid & 63;
      const float* aw = A_w + (size_t)(h*64 + s)*64;
      const float* st = state + (size_t)(h*4 + b)*64;
      float a0=A_b[h*64+s], a1=0.f, a2=0.f, a3=0.f;
      #pragma unroll 4
      for (int j = 0; j < 64; j += 4){
        a0 += aw[j]*st[j]; a1 += aw[j+1]*st[j+1];
        a2 += aw[j+2]*st[j+2]; a3 += aw[j+3]*st[j+3];
      }
      float v = (a0+a1)+(a2+a3);
      a_state[(h*4 + b)*64 + s] = v;
      asl[b][s] = v;
    }
    __syncthreads();
    { // bias_f[b][h*64+d]
      const int b = tid >> 6, d = tid & 63;
      const float* cw = C_w + (size_t)(h*64 + d)*64;
      float a0=C_b[h*64+d], a1=0.f, a2=0.f, a3=0.f;
      #pragma unroll 4
      for (int s = 0; s < 64; s += 4){
        a0 += cw[s]*asl[b][s]; a1 += cw[s+1]*asl[b][s+1];
        a2 += cw[s+2]*asl[b][s+2]; a3 += cw[s+3]*asl[b][s+3];
      }
      bias_f[b*1024 + h*64 + d] = (a0+a1)+(a2+a3);
    }
  }
}

// ---------------- KFUSE (4096 blocks): [0,2048) k4-role ; [2048,4096) k23-role -------
__global__ __launch_bounds__(256) void kfuse(const float* __restrict__ x,
                                             const float* __restrict__ sm,
                                             const float* __restrict__ a_state,
                                             const float* __restrict__ Wo,
                                             const float* __restrict__ Mh,
                                             const float* __restrict__ bias_f,
                                             const float* __restrict__ bo,
                                             unsigned short* __restrict__ xb,
                                             float* __restrict__ out2,
                                             unsigned short* __restrict__ Wb,
                                             float* __restrict__ constb){
  __shared__ alignas(16) char smem[27648];
  const int gblk = blockIdx.x, tid = threadIdx.x;
  if (gblk < 2048){
    // ---------------- k4 role ----------------
    unsigned short* Xs = (unsigned short*)smem;            // 128*72 shorts = 18432 B
    unsigned short* Ss = (unsigned short*)(smem + 18432);  //  64*72 shorts =  9216 B
    const int lin = gblk;
    const int tb = lin & 31, h = (lin >> 5) & 15, b = lin >> 9;
    const int lane = tid & 63, w = tid >> 6;
    const int l15 = lane & 15, l4 = lane >> 4;

    { // stage sm[h] (f32) -> Ss bf16 (row stride 72)
      const float* src = sm + (size_t)h*4096;
      #pragma unroll
      for (int cc = 0; cc < 4; ++cc){
        int c = cc*256 + tid;
        int s = c >> 4, c4 = c & 15;
        float4 v = *(const float4*)&src[s*64 + c4*4];
        uint2 pk = make_uint2(f2bf(v.x) | (f2bf(v.y)<<16), f2bf(v.z) | (f2bf(v.w)<<16));
        *(uint2*)&Ss[s*72 + c4*4] = pk;
      }
    }
    { // stage x slice -> Xs bf16 (stride 72) and xb global (row-major, 16B granules)
      const int row0 = b*Tz + tb*128;
      #pragma unroll
      for (int it = 0; it < 4; ++it){
        int id = it*256 + tid;
        int r = id >> 3, c8 = id & 7;
        const float* px = x + (size_t)(row0 + r)*1024 + h*64 + c8*8;
        float4 v0 = *(const float4*)px, v1 = *(const float4*)(px + 4);
        uint4 pk;
        pk.x = f2bf(v0.x) | (f2bf(v0.y)<<16);
        pk.y = f2bf(v0.z) | (f2bf(v0.w)<<16);
        pk.z = f2bf(v1.x) | (f2bf(v1.y)<<16);
        pk.w = f2bf(v1.z) | (f2bf(v1.w)<<16);
        *(uint4*)&Xs[r*72 + c8*8] = pk;
        *(uint4*)(xb + (size_t)(row0 + r)*1024 + h*64 + c8*8) = pk;
      }
    }
    __syncthreads();

    f32x4 acc[2][4];
    #pragma unroll
    for (int j = 0; j < 4; ++j){
      float4 as4 = *(const float4*)&a_state[(h*4 + b)*64 + j*16 + l4*4];
      f32x4 a0; a0[0]=as4.x; a0[1]=as4.y; a0[2]=as4.z; a0[3]=as4.w;
      acc[0][j] = a0; acc[1][j] = a0;
    }
    #pragma unroll
    for (int kk = 0; kk < 2; ++kk){
      short8 a[2], bb[4];
      #pragma unroll
      for (int i = 0; i < 2; ++i)
        a[i] = *(const short8*)(&Xs[(w*32 + i*16 + l15)*72 + kk*32 + l4*8]);
      #pragma unroll
      for (int j = 0; j < 4; ++j)
        bb[j] = *(const short8*)(&Ss[(j*16 + l15)*72 + kk*32 + l4*8]);
      #pragma unroll
      for (int i = 0; i < 2; ++i)
        #pragma unroll
        for (int j = 0; j < 4; ++j)
          acc[i][j] = __builtin_amdgcn_mfma_f32_16x16x32_bf16(bb[j], a[i], acc[i][j], 0, 0, 0);
    }
    const size_t base = (size_t)h*1048576 + ((size_t)b*4096 + tb*128)*64;
    #pragma unroll
    for (int i = 0; i < 2; ++i)
      #pragma unroll
      for (int j = 0; j < 4; ++j){
        float4 o = make_float4(acc[i][j][0], acc[i][j][1], acc[i][j][2], acc[i][j][3]);
        *(float4*)(out2 + base + (size_t)(w*32 + i*16 + l15)*64 + j*16 + l4*4) = o;
      }
  } else if (gblk < 3072){
    // ---------------- k23 role: Wb ----------------
    float* Mh_l = (float*)smem;
    const int blk = gblk - 2048;
    const int h = blk >> 6, ec = blk & 63;
    #pragma unroll
    for (int it = 0; it < 4; ++it){
      int c = it*256 + tid;
      *(float4*)&Mh_l[c*4] = *(const float4*)&Mh[(size_t)h*4096 + c*4];
    }
    __syncthreads();
    const int dp = tid & 63, er = tid >> 6;
    #pragma unroll
    for (int ee = 0; ee < 4; ++ee){
      const int e = ec*16 + er*4 + ee;
      const float* wo = Wo + (size_t)e*1024 + h*64;
      float a0=0.f,a1=0.f,a2=0.f,a3=0.f;
      #pragma unroll 4
      for (int d = 0; d < 64; d += 4){
        a0 += wo[d]*Mh_l[d*64+dp];     a1 += wo[d+1]*Mh_l[(d+1)*64+dp];
        a2 += wo[d+2]*Mh_l[(d+2)*64+dp]; a3 += wo[d+3]*Mh_l[(d+3)*64+dp];
      }
      Wb[(size_t)e*1024 + h*64 + dp] = (unsigned short)f2bf((a0+a1)+(a2+a3));
    }
  } else {
    // ---------------- k23 role: constb ----------------
    const int idx = (gblk - 3072)*4 + (tid >> 6), lane = tid & 63;
    const int b = idx >> 10, e = idx & 1023;
    const float4* wo = (const float4*)(Wo + (size_t)e*1024);
    const float4* bf = (const float4*)(bias_f + (size_t)b*1024);
    float acc = 0.f;
    #pragma unroll
    for (int i = 0; i < 4; ++i){
      float4 w = wo[i*64 + lane], v = bf[i*64 + lane];
      acc += w.x*v.x + w.y*v.y + w.z*v.z + w.w*v.w;
    }
    acc += __shfl_down(acc, 32); acc += __shfl_down(acc, 16); acc += __shfl_down(acc, 8);
    acc += __shfl_down(acc, 4);  acc += __shfl_down(acc, 2);  acc += __shfl_down(acc, 1);
    if (lane == 0) constb[b*1024 + e] = bo[e] + acc;
  }
}

// ---------------- K5: out = xb @ Wb^T + const  (256x128 tile, 3-deep, 2 blocks/CU) ---
// 512 blocks, 512 thr (8 waves 2Mx4N: wave 128 rows x 32 cols). Stage tile t+2 during
// t; in-flight 6 loads; boundary vmcnt(3) (t<=29), vmcnt(0) at t=30. Proven R13 config.
__global__ __launch_bounds__(512, 2) void k5_gemm(const unsigned short* __restrict__ xb,
                                                  const unsigned short* __restrict__ Wb,
                                                  const float* __restrict__ constb,
                                                  float* __restrict__ out){
  __shared__ alignas(16) unsigned short ldsA[3][8192];   // 256 rows x 32 bf16 per buf
  __shared__ alignas(16) unsigned short ldsB[3][4096];   // 128 rows x 32 bf16 per buf
  const int blk = blockIdx.x;
  const int swz = (blk & 7)*64 + (blk >> 3);     // 512 blocks, 8 XCD chunks of 64
  const int bm = (swz >> 3)*256, bn = (swz & 7)*128;
  const int tid = threadIdx.x;
  const int lane = tid & 63, w = tid >> 6;       // 8 waves
  const int l15 = lane & 15, l4 = lane >> 4;
  const int wr = w >> 2, wc = w & 3;             // 2 (M, 128 rows) x 4 (N, 32 cols)

  // staging source mapping: linear slot L -> logical (row r, 16B-seg g)
  const unsigned short* srcA[2];
  const unsigned short* srcB0;
  #pragma unroll
  for (int q = 0; q < 2; ++q){
    int L = q*512 + tid;
    int b = ((L>>2)&1) ^ ((L>>4)&1);
    int r = (L>>3)*2 + b;
    int g = (L&3) ^ ((((L>>3)&1)<<1) | b);
    srcA[q] = xb + (size_t)(bm + r)*1024 + g*8;
  }
  {
    int L = tid;
    int b = ((L>>2)&1) ^ ((L>>4)&1);
    int r = (L>>3)*2 + b;
    int g = (L&3) ^ ((((L>>3)&1)<<1) | b);
    srcB0 = Wb + (size_t)(bn + r)*1024 + g*8;
  }
  const int dstoff = tid*8;                       // shorts
  const int lane_off = ((l15*4 + l4) ^ (l15 & 7))*8;

  // prologue: stage tiles 0,1,2 (9 GLL/thread, FIFO order A0,A1,B per tile)
  #pragma unroll
  for (int t = 0; t < 3; ++t){
    GLL16(srcA[0] + t*32, &ldsA[t][dstoff]);
    GLL16(srcA[1] + t*32, &ldsA[t][4096 + dstoff]);
    GLL16(srcB0  + t*32, &ldsB[t][dstoff]);
  }
  asm volatile("s_waitcnt vmcnt(6)" ::: "memory");   // tiles 1,2 (6 loads) in flight
  __builtin_amdgcn_s_barrier();
  asm volatile("" ::: "memory");

  f32x4 acc[8][2] = {};
  int cur = 0, stg = 2;

  for (int t = 0; t < 32; ++t){
    const unsigned short* At = &ldsA[cur][0];
    const unsigned short* Bt = &ldsB[cur][0];
    short8 bfr0, bfr1, afr[4];
    // ---- phase A: B-frags + A-frags 0..3, stage A of tile t+2, 8 MFMA
    bfr0 = *(const short8*)(Bt + (wc*32 +  0)*32 + lane_off);
    bfr1 = *(const short8*)(Bt + (wc*32 + 16)*32 + lane_off);
    #pragma unroll
    for (int i = 0; i < 4; ++i)
      afr[i] = *(const short8*)(At + (wr*128 + i*16)*32 + lane_off);
    if (t <= 29){
      GLL16(srcA[0] + (t+2)*32, &ldsA[stg][dstoff]);
      GLL16(srcA[1] + (t+2)*32, &ldsA[stg][4096 + dstoff]);
    }
    __builtin_amdgcn_s_setprio(1);
    #pragma unroll
    for (int i = 0; i < 4; ++i){
      acc[i][0] = __builtin_amdgcn_mfma_f32_16x16x32_bf16(bfr0, afr[i], acc[i][0], 0, 0, 0);
      acc[i][1] = __builtin_amdgcn_mfma_f32_16x16x32_bf16(bfr1, afr[i], acc[i][1], 0, 0, 0);
    }
    __builtin_amdgcn_s_setprio(0);
    // ---- phase B: A-frags 4..7, stage B of tile t+2, 8 MFMA
    #pragma unroll
    for (int i = 0; i < 4; ++i)
      afr[i] = *(const short8*)(At + (wr*128 + (4 + i)*16)*32 + lane_off);
    if (t <= 29)
      GLL16(srcB0 + (t+2)*32, &ldsB[stg][dstoff]);
    __builtin_amdgcn_s_setprio(1);
    #pragma unroll
    for (int i = 0; i < 4; ++i){
      acc[4+i][0] = __builtin_amdgcn_mfma_f32_16x16x32_bf16(bfr0, afr[i], acc[4+i][0], 0, 0, 0);
      acc[4+i][1] = __builtin_amdgcn_mfma_f32_16x16x32_bf16(bfr1, afr[i], acc[4+i][1], 0, 0, 0);
    }
    __builtin_amdgcn_s_setprio(0);
    // ---- boundary: keep t+2's 3 loads in flight; drain only at t=30
    if (t <= 29)      { asm volatile("s_waitcnt vmcnt(3)" ::: "memory"); }
    else if (t == 30) { asm volatile("s_waitcnt vmcnt(0)" ::: "memory"); }
    if (t < 31){
      __builtin_amdgcn_s_barrier();
      asm volatile("" ::: "memory");
    }
    cur = (cur == 2) ? 0 : cur + 1;
    stg = (stg == 2) ? 0 : stg + 1;
  }

  // epilogue: D cols(l15)=t-row, regs(l4*4+q)=e-col
  const int bb = bm >> 12;
  #pragma unroll
  for (int j = 0; j < 2; ++j){
    int n0 = bn + wc*32 + j*16 + l4*4;
    float4 cv = *(const float4*)&constb[bb*1024 + n0];
    #pragma unroll
    for (int i = 0; i < 8; ++i){
      int trow = bm + wr*128 + i*16 + l15;
      float4 o = make_float4(acc[i][j][0] + cv.x, acc[i][j][1] + cv.y,
                             acc[i][j][2] + cv.z, acc[i][j][3] + cv.w);
      *(float4*)(out + (size_t)trow*1024 + n0) = o;
    }
  }
}

extern "C" void kernel_launch(void* const* d_in, const int* in_sizes, int n_in,
                              void* d_out, int out_size, void* d_ws, size_t ws_size,
                              hipStream_t stream){
  const float* x     = (const float*)d_in[0];
  const float* state = (const float*)d_in[1];
  const float* A_w   = (const float*)d_in[2];
  const float* A_b   = (const float*)d_in[3];
  const float* C_w   = (const float*)d_in[4];
  const float* C_b   = (const float*)d_in[5];
  const float* sm    = (const float*)d_in[6];
  const float* Wo    = (const float*)d_in[7];
  const float* bo    = (const float*)d_in[8];
  float* out  = (float*)d_out;
  float* out2 = out + (size_t)MTz*Ez;

  char* ws = (char*)d_ws;
  float* a_state          = (float*)(ws + 0);                 //  16 KiB
  float* Mh               = (float*)(ws + 16384);             // 256 KiB
  float* bias_f           = (float*)(ws + 278528);            //  16 KiB
  float* constb           = (float*)(ws + 294912);            //  16 KiB
  unsigned short* Wb      = (unsigned short*)(ws + 311296);   //   2 MiB
  unsigned short* xb      = (unsigned short*)(ws + 2408448);  //  32 MiB

  k1_pre<<<64, 256, 0, stream>>>(state, A_w, A_b, C_w, C_b, sm, a_state, Mh, bias_f);
  kfuse<<<4096, 256, 0, stream>>>(x, sm, a_state, Wo, Mh, bias_f, bo,
                                  xb, out2, Wb, constb);
  k5_gemm<<<512, 512, 0, stream>>>(xb, Wb, constb, out);
}